// Round 2
// baseline (1072.569 us; speedup 1.0000x reference)
//
#include <hip/hip_runtime.h>
#include <hip/hip_bf16.h>

#define NNODES 10000
#define NEDGES 320000
#define ETOT   (NEDGES + NNODES)
#define NGRAPH 100
#define CH     250   // HEADS*OUT
#define HOUT   125

// ---------------- CSR build (counting sort by dst) ----------------
__global__ void k_deg(const int* __restrict__ eidx, int* __restrict__ deg){
  int e = blockIdx.x*blockDim.x + threadIdx.x;
  if (e >= ETOT) return;
  int dst = (e < NEDGES) ? eidx[NEDGES + e] : (e - NEDGES);
  atomicAdd(&deg[dst], 1);
}

__global__ void k_scan(const int* __restrict__ deg, int* __restrict__ rowptr){
  __shared__ int sh[1024];
  __shared__ int carry;
  if (threadIdx.x == 0){ carry = 0; rowptr[0] = 0; }
  __syncthreads();
  for (int base = 0; base < NNODES; base += 1024){
    int i = base + threadIdx.x;
    int v = (i < NNODES) ? deg[i] : 0;
    sh[threadIdx.x] = v;
    __syncthreads();
    for (int off = 1; off < 1024; off <<= 1){
      int t = (threadIdx.x >= off) ? sh[threadIdx.x - off] : 0;
      __syncthreads();
      sh[threadIdx.x] += t;
      __syncthreads();
    }
    if (i < NNODES) rowptr[i+1] = carry + sh[threadIdx.x];
    __syncthreads();
    if (threadIdx.x == 1023) carry += sh[1023];
    __syncthreads();
  }
}

__global__ void k_fill(const int* __restrict__ eidx, const int* __restrict__ rowptr,
                       int* __restrict__ cursor, int* __restrict__ eids){
  int e = blockIdx.x*blockDim.x + threadIdx.x;
  if (e >= ETOT) return;
  int dst = (e < NEDGES) ? eidx[NEDGES + e] : (e - NEDGES);
  int pos = atomicAdd(&cursor[dst], 1);
  eids[rowptr[dst] + pos] = e;
}

// ---------------- GEMM: C[M,Ncl] = A[M,K] @ W[K,Ncl]  (all fp32) ----------------
#define BM 64
#define BN 64
#define BK 16
__global__ void k_gemm(const float* __restrict__ A, const float* __restrict__ W,
                       float* __restrict__ C, int M, int K, int Ncl){
  __shared__ float As[BK][BM+1];
  __shared__ float Bs[BK][BN+1];
  int tid = threadIdx.x;
  int bm = blockIdx.x * BM, bn = blockIdx.y * BN;
  int tx = tid & 15, ty = tid >> 4;
  float acc[4][4] = {};
  for (int k0 = 0; k0 < K; k0 += BK){
    int r  = tid >> 2;
    int kk = (tid & 3) * 4;
    #pragma unroll
    for (int u = 0; u < 4; ++u){
      int gk = k0 + kk + u;
      float v = 0.f;
      if (bm + r < M && gk < K) v = A[(size_t)(bm + r) * K + gk];
      As[kk + u][r] = v;
    }
    int krow = tid >> 4;
    int nc   = (tid & 15) * 4;
    #pragma unroll
    for (int u = 0; u < 4; ++u){
      int gn = bn + nc + u;
      int gk = k0 + krow;
      float v = 0.f;
      if (gk < K && gn < Ncl) v = W[(size_t)gk * Ncl + gn];
      Bs[krow][nc + u] = v;
    }
    __syncthreads();
    #pragma unroll
    for (int k = 0; k < BK; ++k){
      float a[4], b[4];
      #pragma unroll
      for (int u = 0; u < 4; ++u){ a[u] = As[k][ty*4+u]; b[u] = Bs[k][tx*4+u]; }
      #pragma unroll
      for (int i = 0; i < 4; ++i)
        #pragma unroll
        for (int j = 0; j < 4; ++j)
          acc[i][j] += a[i] * b[j];
    }
    __syncthreads();
  }
  #pragma unroll
  for (int i = 0; i < 4; ++i){
    int row = bm + ty*4 + i;
    if (row >= M) continue;
    #pragma unroll
    for (int j = 0; j < 4; ++j){
      int col = bn + tx*4 + j;
      if (col < Ncl) C[(size_t)row * Ncl + col] = acc[i][j];
    }
  }
}

// ---------------- per-node attention scores e_src, e_dst ----------------
__global__ void k_scores(const float* __restrict__ h, const float* __restrict__ asrc,
                         const float* __restrict__ adst,
                         float* __restrict__ esrc, float* __restrict__ edst){
  int node = (blockIdx.x * blockDim.x + threadIdx.x) >> 6;
  int lane = threadIdx.x & 63;
  if (node >= NNODES) return;
  const float* hr = h + (size_t)node * CH;
  float s0=0,d0=0,s1=0,d1=0;
  for (int j = lane; j < HOUT; j += 64){
    float v0 = hr[j];
    float v1 = hr[HOUT + j];
    s0 += v0 * asrc[j];       d0 += v0 * adst[j];
    s1 += v1 * asrc[HOUT+j];  d1 += v1 * adst[HOUT+j];
  }
  for (int off = 32; off > 0; off >>= 1){
    s0 += __shfl_xor(s0, off);
    d0 += __shfl_xor(d0, off);
    s1 += __shfl_xor(s1, off);
    d1 += __shfl_xor(d1, off);
  }
  if (lane == 0){
    esrc[node*2+0] = s0; esrc[node*2+1] = s1;
    edst[node*2+0] = d0; edst[node*2+1] = d1;
  }
}

// ---------------- per-node softmax + gather-aggregate (+bias, relu) ----------------
__global__ void k_attn_agg(const float* __restrict__ h, const float* __restrict__ esrc,
                           const float* __restrict__ edst, const int* __restrict__ rowptr,
                           const int* __restrict__ eids, const int* __restrict__ eidx,
                           const float* __restrict__ bias, float* __restrict__ out){
  int node = (blockIdx.x * blockDim.x + threadIdx.x) >> 6;
  int lane = threadIdx.x & 63;
  if (node >= NNODES) return;
  int start = rowptr[node], end = rowptr[node+1];
  float ed0 = edst[node*2+0], ed1 = edst[node*2+1];
  // pass 1: max per head
  float mx0 = -1e30f, mx1 = -1e30f;
  for (int i = start + lane; i < end; i += 64){
    int e = eids[i];
    int src = (e < NEDGES) ? eidx[e] : (e - NEDGES);
    float e0 = esrc[src*2+0] + ed0; e0 = e0 > 0.f ? e0 : 0.2f*e0;
    float e1 = esrc[src*2+1] + ed1; e1 = e1 > 0.f ? e1 : 0.2f*e1;
    mx0 = fmaxf(mx0, e0); mx1 = fmaxf(mx1, e1);
  }
  for (int off = 32; off > 0; off >>= 1){
    mx0 = fmaxf(mx0, __shfl_xor(mx0, off));
    mx1 = fmaxf(mx1, __shfl_xor(mx1, off));
  }
  // pass 2: sum of exp
  float sum0 = 0.f, sum1 = 0.f;
  for (int i = start + lane; i < end; i += 64){
    int e = eids[i];
    int src = (e < NEDGES) ? eidx[e] : (e - NEDGES);
    float e0 = esrc[src*2+0] + ed0; e0 = e0 > 0.f ? e0 : 0.2f*e0;
    float e1 = esrc[src*2+1] + ed1; e1 = e1 > 0.f ? e1 : 0.2f*e1;
    sum0 += expf(e0 - mx0); sum1 += expf(e1 - mx1);
  }
  for (int off = 32; off > 0; off >>= 1){
    sum0 += __shfl_xor(sum0, off);
    sum1 += __shfl_xor(sum1, off);
  }
  float inv0 = 1.f / (sum0 + 1e-16f);
  float inv1 = 1.f / (sum1 + 1e-16f);
  // pass 3: weighted gather. lane covers cols {lane, lane+64, lane+128, lane+192}
  bool head1_c1 = (lane + 64) >= HOUT;   // col lane+64: head0 iff < 125
  float acc0=0.f, acc1=0.f, acc2=0.f, acc3=0.f;
  for (int i = start; i < end; ++i){
    int e = eids[i];
    int src = (e < NEDGES) ? eidx[e] : (e - NEDGES);
    float e0 = esrc[src*2+0] + ed0; e0 = e0 > 0.f ? e0 : 0.2f*e0;
    float e1 = esrc[src*2+1] + ed1; e1 = e1 > 0.f ? e1 : 0.2f*e1;
    float a0 = expf(e0 - mx0) * inv0;
    float a1 = expf(e1 - mx1) * inv1;
    const float* hr = h + (size_t)src * CH;
    acc0 += a0 * hr[lane];
    acc1 += (head1_c1 ? a1 : a0) * hr[lane + 64];
    acc2 += a1 * hr[lane + 128];
    if (lane + 192 < CH) acc3 += a1 * hr[lane + 192];
  }
  float* outr = out + (size_t)node * CH;
  float v;
  v = acc0 + bias[lane];        outr[lane]       = v > 0.f ? v : 0.f;
  v = acc1 + bias[lane + 64];   outr[lane + 64]  = v > 0.f ? v : 0.f;
  v = acc2 + bias[lane + 128];  outr[lane + 128] = v > 0.f ? v : 0.f;
  if (lane + 192 < CH){
    v = acc3 + bias[lane + 192]; outr[lane + 192] = v > 0.f ? v : 0.f;
  }
}

// ---------------- global mean pool (sum+count via atomics, zeroed buffers) ----------------
__global__ void k_pool(const float* __restrict__ x, const int* __restrict__ batch,
                       float* __restrict__ g, float* __restrict__ cnt){
  int idx = blockIdx.x*blockDim.x + threadIdx.x;
  if (idx >= NNODES * CH) return;
  int n = idx / CH, c = idx % CH;
  int b = batch[n];
  atomicAdd(&g[(size_t)b * CH + c], x[idx]);
  if (c == 0) atomicAdd(&cnt[b], 1.0f);
}

// ---------------- small dense linear: out = act((A@W)*scale + b) ----------------
__global__ void k_linear(const float* __restrict__ A, const float* __restrict__ W,
                         const float* __restrict__ bias, const float* __restrict__ cnt,
                         float* __restrict__ out, int M, int K, int Ncl, int relu){
  int idx = blockIdx.x*blockDim.x + threadIdx.x;
  if (idx >= M * Ncl) return;
  int r = idx / Ncl, c = idx % Ncl;
  float scale = 1.f;
  if (cnt){ scale = 1.f / fmaxf(cnt[r], 1.f); }
  const float* ar = A + (size_t)r * K;
  float acc = 0.f;
  for (int k = 0; k < K; ++k) acc += ar[k] * W[(size_t)k * Ncl + c];
  acc = acc * scale + bias[c];
  if (relu) acc = fmaxf(acc, 0.f);
  out[idx] = acc;
}

// ---------------- launch ----------------
extern "C" void kernel_launch(void* const* d_in, const int* in_sizes, int n_in,
                              void* d_out, int out_size, void* d_ws, size_t ws_size,
                              hipStream_t stream){
  const float* x   = (const float*)d_in[0];
  const int* eidx  = (const int*)d_in[1];
  const int* batch = (const int*)d_in[2];

  char* ws = (char*)d_ws;
  size_t off = 0;
  auto alloc = [&](size_t bytes)->void*{
    void* p = ws + off;
    off = (off + bytes + 255) & ~(size_t)255;
    return p;
  };
  float* xbuf   = (float*)alloc((size_t)NNODES * CH * 4);    // layer outputs (250-stride)
  float* hbuf   = (float*)alloc((size_t)NNODES * CH * 4);    // GEMM output h
  float* esrc   = (float*)alloc((size_t)NNODES * 2 * 4);
  float* edst   = (float*)alloc((size_t)NNODES * 2 * 4);
  int*   deg    = (int*)  alloc((size_t)NNODES * 4);
  int*   rowptr = (int*)  alloc((size_t)(NNODES + 1) * 4);
  int*   cursor = (int*)  alloc((size_t)NNODES * 4);
  int*   eids   = (int*)  alloc((size_t)ETOT * 4);
  float* g      = (float*)alloc((size_t)NGRAPH * CH * 4);
  float* cnt    = (float*)alloc((size_t)NGRAPH * 4);
  float* m1     = (float*)alloc((size_t)NGRAPH * 200 * 4);
  float* m2     = (float*)alloc((size_t)NGRAPH * 100 * 4);
  float* m3     = (float*)alloc((size_t)NGRAPH * 100 * 4);

  hipMemsetAsync(deg,    0, (size_t)NNODES * 4, stream);
  hipMemsetAsync(cursor, 0, (size_t)NNODES * 4, stream);
  hipMemsetAsync(g,      0, (size_t)NGRAPH * CH * 4, stream);
  hipMemsetAsync(cnt,    0, (size_t)NGRAPH * 4, stream);

  k_deg <<<(ETOT + 255)/256, 256, 0, stream>>>(eidx, deg);
  k_scan<<<1, 1024, 0, stream>>>(deg, rowptr);
  k_fill<<<(ETOT + 255)/256, 256, 0, stream>>>(eidx, rowptr, cursor, eids);

  int Kdims[4] = {336, CH, CH, CH};
  for (int L = 0; L < 4; ++L){
    const float* W   = (const float*)d_in[3 + 4*L];
    const float* as_ = (const float*)d_in[4 + 4*L];
    const float* ad_ = (const float*)d_in[5 + 4*L];
    const float* bb  = (const float*)d_in[6 + 4*L];
    const float* Ain = (L == 0) ? x : xbuf;
    dim3 gg((NNODES + BM - 1)/BM, (CH + BN - 1)/BN);
    k_gemm<<<gg, 256, 0, stream>>>(Ain, W, hbuf, NNODES, Kdims[L], CH);
    k_scores<<<(NNODES*64 + 255)/256, 256, 0, stream>>>(hbuf, as_, ad_, esrc, edst);
    k_attn_agg<<<(NNODES*64 + 255)/256, 256, 0, stream>>>(hbuf, esrc, edst, rowptr, eids, eidx, bb, xbuf);
  }

  k_pool<<<(NNODES*CH + 255)/256, 256, 0, stream>>>(xbuf, batch, g, cnt);

  const float* lw1 = (const float*)d_in[19];
  const float* lb1 = (const float*)d_in[20];
  const float* lw2 = (const float*)d_in[21];
  const float* lb2 = (const float*)d_in[22];
  const float* lw3 = (const float*)d_in[23];
  const float* lb3 = (const float*)d_in[24];
  const float* lw4 = (const float*)d_in[25];
  const float* lb4 = (const float*)d_in[26];

  k_linear<<<(NGRAPH*200 + 255)/256, 256, 0, stream>>>(g,  lw1, lb1, cnt,     m1, NGRAPH, 250, 200, 1);
  k_linear<<<(NGRAPH*100 + 255)/256, 256, 0, stream>>>(m1, lw2, lb2, nullptr, m2, NGRAPH, 200, 100, 1);
  k_linear<<<(NGRAPH*100 + 255)/256, 256, 0, stream>>>(m2, lw3, lb3, nullptr, m3, NGRAPH, 100, 100, 1);
  k_linear<<<(NGRAPH*29  + 255)/256, 256, 0, stream>>>(m3, lw4, lb4, nullptr, (float*)d_out, NGRAPH, 100, 29, 0);
}

// Round 3
// 834.333 us; speedup vs baseline: 1.2855x; 1.2855x over previous
//
#include <hip/hip_runtime.h>
#include <hip/hip_bf16.h>

#define NNODES 10000
#define NEDGES 320000
#define ETOT   (NEDGES + NNODES)
#define NGRAPH 100
#define CH     250   // HEADS*OUT
#define HOUT   125

// ---------------- CSR build (counting sort by dst) ----------------
__global__ void k_deg(const int* __restrict__ eidx, int* __restrict__ deg){
  int e = blockIdx.x*blockDim.x + threadIdx.x;
  if (e >= ETOT) return;
  int dst = (e < NEDGES) ? eidx[NEDGES + e] : (e - NEDGES);
  atomicAdd(&deg[dst], 1);
}

__global__ void k_scan(const int* __restrict__ deg, int* __restrict__ rowptr){
  __shared__ int sh[1024];
  __shared__ int carry;
  if (threadIdx.x == 0){ carry = 0; rowptr[0] = 0; }
  __syncthreads();
  for (int base = 0; base < NNODES; base += 1024){
    int i = base + threadIdx.x;
    int v = (i < NNODES) ? deg[i] : 0;
    sh[threadIdx.x] = v;
    __syncthreads();
    for (int off = 1; off < 1024; off <<= 1){
      int t = (threadIdx.x >= off) ? sh[threadIdx.x - off] : 0;
      __syncthreads();
      sh[threadIdx.x] += t;
      __syncthreads();
    }
    if (i < NNODES) rowptr[i+1] = carry + sh[threadIdx.x];
    __syncthreads();
    if (threadIdx.x == 1023) carry += sh[1023];
    __syncthreads();
  }
}

// store src node id directly into CSR slot (removes eidx indirection later)
__global__ void k_fill(const int* __restrict__ eidx, const int* __restrict__ rowptr,
                       int* __restrict__ cursor, int* __restrict__ csr_src){
  int e = blockIdx.x*blockDim.x + threadIdx.x;
  if (e >= ETOT) return;
  int dst, src;
  if (e < NEDGES){ src = eidx[e]; dst = eidx[NEDGES + e]; }
  else           { src = e - NEDGES; dst = src; }
  int pos = atomicAdd(&cursor[dst], 1);
  csr_src[rowptr[dst] + pos] = src;
}

// ---------------- GEMM: C[M,Ncl] = A[M,K] @ W[K,Ncl]  (all fp32) ----------------
#define BM 64
#define BN 64
#define BK 16
__global__ void k_gemm(const float* __restrict__ A, const float* __restrict__ W,
                       float* __restrict__ C, int M, int K, int Ncl){
  __shared__ float As[BK][BM+1];
  __shared__ float Bs[BK][BN+1];
  int tid = threadIdx.x;
  int bm = blockIdx.x * BM, bn = blockIdx.y * BN;
  int tx = tid & 15, ty = tid >> 4;
  float acc[4][4] = {};
  for (int k0 = 0; k0 < K; k0 += BK){
    int r  = tid >> 2;
    int kk = (tid & 3) * 4;
    #pragma unroll
    for (int u = 0; u < 4; ++u){
      int gk = k0 + kk + u;
      float v = 0.f;
      if (bm + r < M && gk < K) v = A[(size_t)(bm + r) * K + gk];
      As[kk + u][r] = v;
    }
    int krow = tid >> 4;
    int nc   = (tid & 15) * 4;
    #pragma unroll
    for (int u = 0; u < 4; ++u){
      int gn = bn + nc + u;
      int gk = k0 + krow;
      float v = 0.f;
      if (gk < K && gn < Ncl) v = W[(size_t)gk * Ncl + gn];
      Bs[krow][nc + u] = v;
    }
    __syncthreads();
    #pragma unroll
    for (int k = 0; k < BK; ++k){
      float a[4], b[4];
      #pragma unroll
      for (int u = 0; u < 4; ++u){ a[u] = As[k][ty*4+u]; b[u] = Bs[k][tx*4+u]; }
      #pragma unroll
      for (int i = 0; i < 4; ++i)
        #pragma unroll
        for (int j = 0; j < 4; ++j)
          acc[i][j] += a[i] * b[j];
    }
    __syncthreads();
  }
  #pragma unroll
  for (int i = 0; i < 4; ++i){
    int row = bm + ty*4 + i;
    if (row >= M) continue;
    #pragma unroll
    for (int j = 0; j < 4; ++j){
      int col = bn + tx*4 + j;
      if (col < Ncl) C[(size_t)row * Ncl + col] = acc[i][j];
    }
  }
}

// ---------------- per-node attention scores e_src, e_dst ----------------
__global__ void k_scores(const float* __restrict__ h, const float* __restrict__ asrc,
                         const float* __restrict__ adst,
                         float* __restrict__ esrc, float* __restrict__ edst){
  int node = (blockIdx.x * blockDim.x + threadIdx.x) >> 6;
  int lane = threadIdx.x & 63;
  if (node >= NNODES) return;
  const float* hr = h + (size_t)node * CH;
  float s0=0,d0=0,s1=0,d1=0;
  for (int j = lane; j < HOUT; j += 64){
    float v0 = hr[j];
    float v1 = hr[HOUT + j];
    s0 += v0 * asrc[j];       d0 += v0 * adst[j];
    s1 += v1 * asrc[HOUT+j];  d1 += v1 * adst[HOUT+j];
  }
  for (int off = 32; off > 0; off >>= 1){
    s0 += __shfl_xor(s0, off);
    d0 += __shfl_xor(d0, off);
    s1 += __shfl_xor(s1, off);
    d1 += __shfl_xor(d1, off);
  }
  if (lane == 0){
    esrc[node*2+0] = s0; esrc[node*2+1] = s1;
    edst[node*2+0] = d0; edst[node*2+1] = d1;
  }
}

// ---------------- per-node softmax -> per-edge alpha (float2 per CSR slot) ----------------
__global__ void k_alpha(const float* __restrict__ esrc, const float* __restrict__ edst,
                        const int* __restrict__ rowptr, const int* __restrict__ csr_src,
                        float2* __restrict__ alpha){
  int node = (blockIdx.x * blockDim.x + threadIdx.x) >> 6;
  int lane = threadIdx.x & 63;
  if (node >= NNODES) return;
  int start = rowptr[node], end = rowptr[node+1];
  float ed0 = edst[node*2+0], ed1 = edst[node*2+1];
  float mx0 = -1e30f, mx1 = -1e30f;
  for (int i = start + lane; i < end; i += 64){
    int src = csr_src[i];
    float e0 = esrc[src*2+0] + ed0; e0 = e0 > 0.f ? e0 : 0.2f*e0;
    float e1 = esrc[src*2+1] + ed1; e1 = e1 > 0.f ? e1 : 0.2f*e1;
    mx0 = fmaxf(mx0, e0); mx1 = fmaxf(mx1, e1);
  }
  for (int off = 32; off > 0; off >>= 1){
    mx0 = fmaxf(mx0, __shfl_xor(mx0, off));
    mx1 = fmaxf(mx1, __shfl_xor(mx1, off));
  }
  float sum0 = 0.f, sum1 = 0.f;
  for (int i = start + lane; i < end; i += 64){
    int src = csr_src[i];
    float e0 = esrc[src*2+0] + ed0; e0 = e0 > 0.f ? e0 : 0.2f*e0;
    float e1 = esrc[src*2+1] + ed1; e1 = e1 > 0.f ? e1 : 0.2f*e1;
    sum0 += expf(e0 - mx0); sum1 += expf(e1 - mx1);
  }
  for (int off = 32; off > 0; off >>= 1){
    sum0 += __shfl_xor(sum0, off);
    sum1 += __shfl_xor(sum1, off);
  }
  float inv0 = 1.f / (sum0 + 1e-16f);
  float inv1 = 1.f / (sum1 + 1e-16f);
  for (int i = start + lane; i < end; i += 64){
    int src = csr_src[i];
    float e0 = esrc[src*2+0] + ed0; e0 = e0 > 0.f ? e0 : 0.2f*e0;
    float e1 = esrc[src*2+1] + ed1; e1 = e1 > 0.f ? e1 : 0.2f*e1;
    alpha[i] = make_float2(expf(e0 - mx0) * inv0, expf(e1 - mx1) * inv1);
  }
}

// ---------------- weighted gather: block(4 waves) per node, LDS cross-wave reduce ----------------
__global__ __launch_bounds__(256) void k_gather(const float* __restrict__ h,
                        const float2* __restrict__ alpha, const int* __restrict__ csr_src,
                        const int* __restrict__ rowptr, const float* __restrict__ bias,
                        float* __restrict__ out){
  int node = blockIdx.x;
  int tid = threadIdx.x, wave = tid >> 6, lane = tid & 63;
  int start = rowptr[node], end = rowptr[node+1];
  // column map per lane: c0=lane(h0), c1=lane+64(h0 iff lane<61), c2=lane+128(h1), c3=lane+192(h1, lane<58)
  bool c1h1 = (lane + 64) >= HOUT;
  bool c3ok = (lane + 192) < CH;
  float acc0=0.f, acc1=0.f, acc2=0.f, acc3=0.f;
  int i = start + wave;
  // unrolled by 2: two independent rows in flight per wave
  for (; i + 4 < end; i += 8){
    int s0 = csr_src[i];
    int s1 = csr_src[i + 4];
    float2 a0 = alpha[i];
    float2 a1 = alpha[i + 4];
    const float* h0 = h + (size_t)s0 * CH;
    const float* h1 = h + (size_t)s1 * CH;
    float w0c1 = c1h1 ? a0.y : a0.x;
    float w1c1 = c1h1 ? a1.y : a1.x;
    acc0 += a0.x * h0[lane];
    acc1 += w0c1 * h0[lane + 64];
    acc2 += a0.y * h0[lane + 128];
    if (c3ok) acc3 += a0.y * h0[lane + 192];
    acc0 += a1.x * h1[lane];
    acc1 += w1c1 * h1[lane + 64];
    acc2 += a1.y * h1[lane + 128];
    if (c3ok) acc3 += a1.y * h1[lane + 192];
  }
  if (i < end){
    int s0 = csr_src[i];
    float2 a0 = alpha[i];
    const float* h0 = h + (size_t)s0 * CH;
    float w0c1 = c1h1 ? a0.y : a0.x;
    acc0 += a0.x * h0[lane];
    acc1 += w0c1 * h0[lane + 64];
    acc2 += a0.y * h0[lane + 128];
    if (c3ok) acc3 += a0.y * h0[lane + 192];
  }
  __shared__ float sh[4 * 256];
  float* shw = sh + wave * 256;
  shw[lane]        = acc0;
  shw[lane + 64]   = acc1;
  shw[lane + 128]  = acc2;
  if (c3ok) shw[lane + 192] = acc3;
  __syncthreads();
  if (tid < CH){
    float v = sh[tid] + sh[256 + tid] + sh[512 + tid] + sh[768 + tid] + bias[tid];
    out[(size_t)node * CH + tid] = v > 0.f ? v : 0.f;
  }
}

// ---------------- global mean pool (sum+count via atomics, zeroed buffers) ----------------
__global__ void k_pool(const float* __restrict__ x, const int* __restrict__ batch,
                       float* __restrict__ g, float* __restrict__ cnt){
  int idx = blockIdx.x*blockDim.x + threadIdx.x;
  if (idx >= NNODES * CH) return;
  int n = idx / CH, c = idx % CH;
  int b = batch[n];
  atomicAdd(&g[(size_t)b * CH + c], x[idx]);
  if (c == 0) atomicAdd(&cnt[b], 1.0f);
}

// ---------------- small dense linear: out = act((A@W)*scale + b) ----------------
__global__ void k_linear(const float* __restrict__ A, const float* __restrict__ W,
                         const float* __restrict__ bias, const float* __restrict__ cnt,
                         float* __restrict__ out, int M, int K, int Ncl, int relu){
  int idx = blockIdx.x*blockDim.x + threadIdx.x;
  if (idx >= M * Ncl) return;
  int r = idx / Ncl, c = idx % Ncl;
  float scale = 1.f;
  if (cnt){ scale = 1.f / fmaxf(cnt[r], 1.f); }
  const float* ar = A + (size_t)r * K;
  float acc = 0.f;
  for (int k = 0; k < K; ++k) acc += ar[k] * W[(size_t)k * Ncl + c];
  acc = acc * scale + bias[c];
  if (relu) acc = fmaxf(acc, 0.f);
  out[idx] = acc;
}

// ---------------- launch ----------------
extern "C" void kernel_launch(void* const* d_in, const int* in_sizes, int n_in,
                              void* d_out, int out_size, void* d_ws, size_t ws_size,
                              hipStream_t stream){
  const float* x   = (const float*)d_in[0];
  const int* eidx  = (const int*)d_in[1];
  const int* batch = (const int*)d_in[2];

  char* ws = (char*)d_ws;
  size_t off = 0;
  auto alloc = [&](size_t bytes)->void*{
    void* p = ws + off;
    off = (off + bytes + 255) & ~(size_t)255;
    return p;
  };
  float*  xbuf    = (float*) alloc((size_t)NNODES * CH * 4);   // layer outputs (250-stride)
  float*  hbuf    = (float*) alloc((size_t)NNODES * CH * 4);   // GEMM output h
  float*  esrc    = (float*) alloc((size_t)NNODES * 2 * 4);
  float*  edst    = (float*) alloc((size_t)NNODES * 2 * 4);
  int*    deg     = (int*)   alloc((size_t)NNODES * 4);
  int*    rowptr  = (int*)   alloc((size_t)(NNODES + 1) * 4);
  int*    cursor  = (int*)   alloc((size_t)NNODES * 4);
  int*    csr_src = (int*)   alloc((size_t)ETOT * 4);
  float2* alpha   = (float2*)alloc((size_t)ETOT * 8);
  float*  g       = (float*) alloc((size_t)NGRAPH * CH * 4);
  float*  cnt     = (float*) alloc((size_t)NGRAPH * 4);
  float*  m1      = (float*) alloc((size_t)NGRAPH * 200 * 4);
  float*  m2      = (float*) alloc((size_t)NGRAPH * 100 * 4);
  float*  m3      = (float*) alloc((size_t)NGRAPH * 100 * 4);

  hipMemsetAsync(deg,    0, (size_t)NNODES * 4, stream);
  hipMemsetAsync(cursor, 0, (size_t)NNODES * 4, stream);
  hipMemsetAsync(g,      0, (size_t)NGRAPH * CH * 4, stream);
  hipMemsetAsync(cnt,    0, (size_t)NGRAPH * 4, stream);

  k_deg <<<(ETOT + 255)/256, 256, 0, stream>>>(eidx, deg);
  k_scan<<<1, 1024, 0, stream>>>(deg, rowptr);
  k_fill<<<(ETOT + 255)/256, 256, 0, stream>>>(eidx, rowptr, cursor, csr_src);

  int Kdims[4] = {336, CH, CH, CH};
  for (int L = 0; L < 4; ++L){
    const float* W   = (const float*)d_in[3 + 4*L];
    const float* as_ = (const float*)d_in[4 + 4*L];
    const float* ad_ = (const float*)d_in[5 + 4*L];
    const float* bb  = (const float*)d_in[6 + 4*L];
    const float* Ain = (L == 0) ? x : xbuf;
    dim3 gg((NNODES + BM - 1)/BM, (CH + BN - 1)/BN);
    k_gemm<<<gg, 256, 0, stream>>>(Ain, W, hbuf, NNODES, Kdims[L], CH);
    k_scores<<<(NNODES*64 + 255)/256, 256, 0, stream>>>(hbuf, as_, ad_, esrc, edst);
    k_alpha <<<(NNODES*64 + 255)/256, 256, 0, stream>>>(esrc, edst, rowptr, csr_src, alpha);
    k_gather<<<NNODES, 256, 0, stream>>>(hbuf, alpha, csr_src, rowptr, bb, xbuf);
  }

  k_pool<<<(NNODES*CH + 255)/256, 256, 0, stream>>>(xbuf, batch, g, cnt);

  const float* lw1 = (const float*)d_in[19];
  const float* lb1 = (const float*)d_in[20];
  const float* lw2 = (const float*)d_in[21];
  const float* lb2 = (const float*)d_in[22];
  const float* lw3 = (const float*)d_in[23];
  const float* lb3 = (const float*)d_in[24];
  const float* lw4 = (const float*)d_in[25];
  const float* lb4 = (const float*)d_in[26];

  k_linear<<<(NGRAPH*200 + 255)/256, 256, 0, stream>>>(g,  lw1, lb1, cnt,     m1, NGRAPH, 250, 200, 1);
  k_linear<<<(NGRAPH*100 + 255)/256, 256, 0, stream>>>(m1, lw2, lb2, nullptr, m2, NGRAPH, 200, 100, 1);
  k_linear<<<(NGRAPH*100 + 255)/256, 256, 0, stream>>>(m2, lw3, lb3, nullptr, m3, NGRAPH, 100, 100, 1);
  k_linear<<<(NGRAPH*29  + 255)/256, 256, 0, stream>>>(m3, lw4, lb4, nullptr, (float*)d_out, NGRAPH, 100, 29, 0);
}

// Round 4
// 779.533 us; speedup vs baseline: 1.3759x; 1.0703x over previous
//
#include <hip/hip_runtime.h>
#include <hip/hip_bf16.h>

#define NNODES 10000
#define NEDGES 320000
#define ETOT   (NEDGES + NNODES)
#define NGRAPH 100
#define CH     250   // HEADS*OUT
#define HOUT   125

// ---------------- CSR build (counting sort by dst) ----------------
__global__ void k_deg(const int* __restrict__ eidx, int* __restrict__ deg){
  int e = blockIdx.x*blockDim.x + threadIdx.x;
  if (e >= ETOT) return;
  int dst = (e < NEDGES) ? eidx[NEDGES + e] : (e - NEDGES);
  atomicAdd(&deg[dst], 1);
}

__global__ void k_scan(const int* __restrict__ deg, int* __restrict__ rowptr){
  __shared__ int sh[1024];
  __shared__ int carry;
  if (threadIdx.x == 0){ carry = 0; rowptr[0] = 0; }
  __syncthreads();
  for (int base = 0; base < NNODES; base += 1024){
    int i = base + threadIdx.x;
    int v = (i < NNODES) ? deg[i] : 0;
    sh[threadIdx.x] = v;
    __syncthreads();
    for (int off = 1; off < 1024; off <<= 1){
      int t = (threadIdx.x >= off) ? sh[threadIdx.x - off] : 0;
      __syncthreads();
      sh[threadIdx.x] += t;
      __syncthreads();
    }
    if (i < NNODES) rowptr[i+1] = carry + sh[threadIdx.x];
    __syncthreads();
    if (threadIdx.x == 1023) carry += sh[1023];
    __syncthreads();
  }
}

// store src node id directly into CSR slot
__global__ void k_fill(const int* __restrict__ eidx, const int* __restrict__ rowptr,
                       int* __restrict__ cursor, int* __restrict__ csr_src){
  int e = blockIdx.x*blockDim.x + threadIdx.x;
  if (e >= ETOT) return;
  int dst, src;
  if (e < NEDGES){ src = eidx[e]; dst = eidx[NEDGES + e]; }
  else           { src = e - NEDGES; dst = src; }
  int pos = atomicAdd(&cursor[dst], 1);
  csr_src[rowptr[dst] + pos] = src;
}

// ---------------- GEMM: C[M,Ncl] = A[M,K] @ W[K,Ncl]  (fp32, 128x64 tile, 8x4 microtile) ----------------
#define BM 128
#define BN 64
#define BK 16
// LDS pads chosen to keep float4 alignment: (BM+4), (BN+4)
__global__ __launch_bounds__(256) void k_gemm(const float* __restrict__ A, const float* __restrict__ W,
                       float* __restrict__ C, int M, int K, int Ncl){
  __shared__ float As[BK][BM+4];   // stride 132 floats = 528 B (16B-aligned rows)
  __shared__ float Bs[BK][BN+4];   // stride 68 floats = 272 B (16B-aligned rows)
  int tid = threadIdx.x;
  int bm = blockIdx.x * BM, bn = blockIdx.y * BN;
  int tx = tid & 15;        // n-tile: cols tx*4 .. tx*4+3
  int ty = tid >> 4;        // m-tile: rows ty*8 .. ty*8+7
  // staging maps
  int ar = tid >> 1;            // 0..127 (A row within tile)
  int ak = (tid & 1) * 8;       // 0 or 8 (A k-base, 8 elems each)
  int bk = tid >> 4;            // 0..15  (B k-row)
  int bn0 = (tid & 15) * 4;     // 0..60  (B col base, 4 elems each)

  float acc[8][4] = {};
  for (int k0 = 0; k0 < K; k0 += BK){
    int grow = bm + ar;
    #pragma unroll
    for (int u = 0; u < 8; ++u){
      int gk = k0 + ak + u;
      float v = 0.f;
      if (grow < M && gk < K) v = A[(size_t)grow * K + gk];
      As[ak + u][ar] = v;
    }
    int gkb = k0 + bk;
    #pragma unroll
    for (int u = 0; u < 4; ++u){
      int gn = bn + bn0 + u;
      float v = 0.f;
      if (gkb < K && gn < Ncl) v = W[(size_t)gkb * Ncl + gn];
      Bs[bk][bn0 + u] = v;
    }
    __syncthreads();
    #pragma unroll
    for (int k = 0; k < BK; ++k){
      float4 a0 = *(const float4*)&As[k][ty*8];
      float4 a1 = *(const float4*)&As[k][ty*8 + 4];
      float4 b0 = *(const float4*)&Bs[k][tx*4];
      float a[8] = {a0.x,a0.y,a0.z,a0.w,a1.x,a1.y,a1.z,a1.w};
      float b[4] = {b0.x,b0.y,b0.z,b0.w};
      #pragma unroll
      for (int i = 0; i < 8; ++i)
        #pragma unroll
        for (int j = 0; j < 4; ++j)
          acc[i][j] += a[i] * b[j];
    }
    __syncthreads();
  }
  #pragma unroll
  for (int i = 0; i < 8; ++i){
    int row = bm + ty*8 + i;
    if (row >= M) continue;
    #pragma unroll
    for (int j = 0; j < 4; ++j){
      int col = bn + tx*4 + j;
      if (col < Ncl) C[(size_t)row * Ncl + col] = acc[i][j];
    }
  }
}

// ---------------- per-node attention scores e_src, e_dst ----------------
__global__ void k_scores(const float* __restrict__ h, const float* __restrict__ asrc,
                         const float* __restrict__ adst,
                         float* __restrict__ esrc, float* __restrict__ edst){
  int node = (blockIdx.x * blockDim.x + threadIdx.x) >> 6;
  int lane = threadIdx.x & 63;
  if (node >= NNODES) return;
  const float* hr = h + (size_t)node * CH;
  float s0=0,d0=0,s1=0,d1=0;
  for (int j = lane; j < HOUT; j += 64){
    float v0 = hr[j];
    float v1 = hr[HOUT + j];
    s0 += v0 * asrc[j];       d0 += v0 * adst[j];
    s1 += v1 * asrc[HOUT+j];  d1 += v1 * adst[HOUT+j];
  }
  for (int off = 32; off > 0; off >>= 1){
    s0 += __shfl_xor(s0, off);
    d0 += __shfl_xor(d0, off);
    s1 += __shfl_xor(s1, off);
    d1 += __shfl_xor(d1, off);
  }
  if (lane == 0){
    esrc[node*2+0] = s0; esrc[node*2+1] = s1;
    edst[node*2+0] = d0; edst[node*2+1] = d1;
  }
}

// ---------------- per-node softmax -> per-edge alpha (float2 per CSR slot) ----------------
__global__ void k_alpha(const float* __restrict__ esrc, const float* __restrict__ edst,
                        const int* __restrict__ rowptr, const int* __restrict__ csr_src,
                        float2* __restrict__ alpha){
  int node = (blockIdx.x * blockDim.x + threadIdx.x) >> 6;
  int lane = threadIdx.x & 63;
  if (node >= NNODES) return;
  int start = rowptr[node], end = rowptr[node+1];
  float ed0 = edst[node*2+0], ed1 = edst[node*2+1];
  float mx0 = -1e30f, mx1 = -1e30f;
  for (int i = start + lane; i < end; i += 64){
    int src = csr_src[i];
    float e0 = esrc[src*2+0] + ed0; e0 = e0 > 0.f ? e0 : 0.2f*e0;
    float e1 = esrc[src*2+1] + ed1; e1 = e1 > 0.f ? e1 : 0.2f*e1;
    mx0 = fmaxf(mx0, e0); mx1 = fmaxf(mx1, e1);
  }
  for (int off = 32; off > 0; off >>= 1){
    mx0 = fmaxf(mx0, __shfl_xor(mx0, off));
    mx1 = fmaxf(mx1, __shfl_xor(mx1, off));
  }
  float sum0 = 0.f, sum1 = 0.f;
  for (int i = start + lane; i < end; i += 64){
    int src = csr_src[i];
    float e0 = esrc[src*2+0] + ed0; e0 = e0 > 0.f ? e0 : 0.2f*e0;
    float e1 = esrc[src*2+1] + ed1; e1 = e1 > 0.f ? e1 : 0.2f*e1;
    sum0 += expf(e0 - mx0); sum1 += expf(e1 - mx1);
  }
  for (int off = 32; off > 0; off >>= 1){
    sum0 += __shfl_xor(sum0, off);
    sum1 += __shfl_xor(sum1, off);
  }
  float inv0 = 1.f / (sum0 + 1e-16f);
  float inv1 = 1.f / (sum1 + 1e-16f);
  for (int i = start + lane; i < end; i += 64){
    int src = csr_src[i];
    float e0 = esrc[src*2+0] + ed0; e0 = e0 > 0.f ? e0 : 0.2f*e0;
    float e1 = esrc[src*2+1] + ed1; e1 = e1 > 0.f ? e1 : 0.2f*e1;
    alpha[i] = make_float2(expf(e0 - mx0) * inv0, expf(e1 - mx1) * inv1);
  }
}

// ---------------- weighted gather: block(4 waves) per node, LDS cross-wave reduce ----------------
__global__ __launch_bounds__(256) void k_gather(const float* __restrict__ h,
                        const float2* __restrict__ alpha, const int* __restrict__ csr_src,
                        const int* __restrict__ rowptr, const float* __restrict__ bias,
                        float* __restrict__ out){
  int node = blockIdx.x;
  int tid = threadIdx.x, wave = tid >> 6, lane = tid & 63;
  int start = rowptr[node], end = rowptr[node+1];
  bool c1h1 = (lane + 64) >= HOUT;
  bool c3ok = (lane + 192) < CH;
  float acc0=0.f, acc1=0.f, acc2=0.f, acc3=0.f;
  int i = start + wave;
  for (; i + 4 < end; i += 8){
    int s0 = csr_src[i];
    int s1 = csr_src[i + 4];
    float2 a0 = alpha[i];
    float2 a1 = alpha[i + 4];
    const float* h0 = h + (size_t)s0 * CH;
    const float* h1 = h + (size_t)s1 * CH;
    float w0c1 = c1h1 ? a0.y : a0.x;
    float w1c1 = c1h1 ? a1.y : a1.x;
    acc0 += a0.x * h0[lane];
    acc1 += w0c1 * h0[lane + 64];
    acc2 += a0.y * h0[lane + 128];
    if (c3ok) acc3 += a0.y * h0[lane + 192];
    acc0 += a1.x * h1[lane];
    acc1 += w1c1 * h1[lane + 64];
    acc2 += a1.y * h1[lane + 128];
    if (c3ok) acc3 += a1.y * h1[lane + 192];
  }
  if (i < end){
    int s0 = csr_src[i];
    float2 a0 = alpha[i];
    const float* h0 = h + (size_t)s0 * CH;
    float w0c1 = c1h1 ? a0.y : a0.x;
    acc0 += a0.x * h0[lane];
    acc1 += w0c1 * h0[lane + 64];
    acc2 += a0.y * h0[lane + 128];
    if (c3ok) acc3 += a0.y * h0[lane + 192];
  }
  __shared__ float sh[4 * 256];
  float* shw = sh + wave * 256;
  shw[lane]        = acc0;
  shw[lane + 64]   = acc1;
  shw[lane + 128]  = acc2;
  if (c3ok) shw[lane + 192] = acc3;
  __syncthreads();
  if (tid < CH){
    float v = sh[tid] + sh[256 + tid] + sh[512 + tid] + sh[768 + tid] + bias[tid];
    out[(size_t)node * CH + tid] = v > 0.f ? v : 0.f;
  }
}

// ---------------- global mean pool ----------------
__global__ void k_pool(const float* __restrict__ x, const int* __restrict__ batch,
                       float* __restrict__ g, float* __restrict__ cnt){
  int idx = blockIdx.x*blockDim.x + threadIdx.x;
  if (idx >= NNODES * CH) return;
  int n = idx / CH, c = idx % CH;
  int b = batch[n];
  atomicAdd(&g[(size_t)b * CH + c], x[idx]);
  if (c == 0) atomicAdd(&cnt[b], 1.0f);
}

// ---------------- small dense linear: block per row, threads = cols ----------------
__global__ void k_linear(const float* __restrict__ A, const float* __restrict__ W,
                         const float* __restrict__ bias, const float* __restrict__ cnt,
                         float* __restrict__ out, int M, int K, int Ncl, int relu){
  int r = blockIdx.x;
  int c = threadIdx.x;
  if (r >= M || c >= Ncl) return;
  float scale = 1.f;
  if (cnt){ scale = 1.f / fmaxf(cnt[r], 1.f); }
  const float* ar = A + (size_t)r * K;
  float acc = 0.f;
  int k = 0;
  for (; k + 4 <= K; k += 4){
    float a0 = ar[k], a1 = ar[k+1], a2 = ar[k+2], a3 = ar[k+3];
    acc += a0 * W[(size_t)k * Ncl + c];
    acc += a1 * W[(size_t)(k+1) * Ncl + c];
    acc += a2 * W[(size_t)(k+2) * Ncl + c];
    acc += a3 * W[(size_t)(k+3) * Ncl + c];
  }
  for (; k < K; ++k) acc += ar[k] * W[(size_t)k * Ncl + c];
  acc = acc * scale + bias[c];
  if (relu) acc = fmaxf(acc, 0.f);
  out[(size_t)r * Ncl + c] = acc;
}

// ---------------- launch ----------------
extern "C" void kernel_launch(void* const* d_in, const int* in_sizes, int n_in,
                              void* d_out, int out_size, void* d_ws, size_t ws_size,
                              hipStream_t stream){
  const float* x   = (const float*)d_in[0];
  const int* eidx  = (const int*)d_in[1];
  const int* batch = (const int*)d_in[2];

  char* ws = (char*)d_ws;
  size_t off = 0;
  auto alloc = [&](size_t bytes)->void*{
    void* p = ws + off;
    off = (off + bytes + 255) & ~(size_t)255;
    return p;
  };
  float*  xbuf    = (float*) alloc((size_t)NNODES * CH * 4);
  float*  hbuf    = (float*) alloc((size_t)NNODES * CH * 4);
  float*  esrc    = (float*) alloc((size_t)NNODES * 2 * 4);
  float*  edst    = (float*) alloc((size_t)NNODES * 2 * 4);
  int*    deg     = (int*)   alloc((size_t)NNODES * 4);
  int*    rowptr  = (int*)   alloc((size_t)(NNODES + 1) * 4);
  int*    cursor  = (int*)   alloc((size_t)NNODES * 4);
  int*    csr_src = (int*)   alloc((size_t)ETOT * 4);
  float2* alpha   = (float2*)alloc((size_t)ETOT * 8);
  float*  g       = (float*) alloc((size_t)NGRAPH * CH * 4);
  float*  cnt     = (float*) alloc((size_t)NGRAPH * 4);
  float*  m1      = (float*) alloc((size_t)NGRAPH * 200 * 4);
  float*  m2      = (float*) alloc((size_t)NGRAPH * 100 * 4);
  float*  m3      = (float*) alloc((size_t)NGRAPH * 100 * 4);

  hipMemsetAsync(deg,    0, (size_t)NNODES * 4, stream);
  hipMemsetAsync(cursor, 0, (size_t)NNODES * 4, stream);
  hipMemsetAsync(g,      0, (size_t)NGRAPH * CH * 4, stream);
  hipMemsetAsync(cnt,    0, (size_t)NGRAPH * 4, stream);

  k_deg <<<(ETOT + 255)/256, 256, 0, stream>>>(eidx, deg);
  k_scan<<<1, 1024, 0, stream>>>(deg, rowptr);
  k_fill<<<(ETOT + 255)/256, 256, 0, stream>>>(eidx, rowptr, cursor, csr_src);

  int Kdims[4] = {336, CH, CH, CH};
  for (int L = 0; L < 4; ++L){
    const float* W   = (const float*)d_in[3 + 4*L];
    const float* as_ = (const float*)d_in[4 + 4*L];
    const float* ad_ = (const float*)d_in[5 + 4*L];
    const float* bb  = (const float*)d_in[6 + 4*L];
    const float* Ain = (L == 0) ? x : xbuf;
    dim3 gg((NNODES + BM - 1)/BM, (CH + BN - 1)/BN);
    k_gemm<<<gg, 256, 0, stream>>>(Ain, W, hbuf, NNODES, Kdims[L], CH);
    k_scores<<<(NNODES*64 + 255)/256, 256, 0, stream>>>(hbuf, as_, ad_, esrc, edst);
    k_alpha <<<(NNODES*64 + 255)/256, 256, 0, stream>>>(esrc, edst, rowptr, csr_src, alpha);
    k_gather<<<NNODES, 256, 0, stream>>>(hbuf, alpha, csr_src, rowptr, bb, xbuf);
  }

  k_pool<<<(NNODES*CH + 255)/256, 256, 0, stream>>>(xbuf, batch, g, cnt);

  const float* lw1 = (const float*)d_in[19];
  const float* lb1 = (const float*)d_in[20];
  const float* lw2 = (const float*)d_in[21];
  const float* lb2 = (const float*)d_in[22];
  const float* lw3 = (const float*)d_in[23];
  const float* lb3 = (const float*)d_in[24];
  const float* lw4 = (const float*)d_in[25];
  const float* lb4 = (const float*)d_in[26];

  k_linear<<<NGRAPH, 256, 0, stream>>>(g,  lw1, lb1, cnt,     m1, NGRAPH, 250, 200, 1);
  k_linear<<<NGRAPH, 256, 0, stream>>>(m1, lw2, lb2, nullptr, m2, NGRAPH, 200, 100, 1);
  k_linear<<<NGRAPH, 256, 0, stream>>>(m2, lw3, lb3, nullptr, m3, NGRAPH, 100, 100, 1);
  k_linear<<<NGRAPH, 256, 0, stream>>>(m3, lw4, lb4, nullptr, (float*)d_out, NGRAPH, 100, 29, 0);
}